// Round 5
// baseline (608.726 us; speedup 1.0000x reference)
//
#include <hip/hip_runtime.h>

#define N_NODES 10000
#define N_EDGES 640000
#define CH 128
#define NBLK 256             // persistent blocks (== CU count)
#define NTHR 256
#define NHB 128              // hist/scatter edge partitions
#define EPB (N_EDGES / NHB)  // 5000 edges per partition
#define NCHUNK 40            // ceil(N_NODES/256)
#define GTILES 157           // ceil(N_NODES/64) gemm tiles

union SMem {
    struct { int h[N_NODES]; float hf[N_NODES]; } hist;    // 80 KB
    struct { int cur[N_NODES]; float di[N_NODES]; } scat;  // 80 KB
    struct { float As[32][68]; float Ws[32][132]; } gemm;  // ~26 KB
    struct { int csum[NCHUNK]; int wsum[4]; } scan;
    int red[4];
};

// Grid-wide soft barrier: monotonically increasing arrival counter.
// All 256 blocks are co-resident (80KB LDS -> 2 blocks/CU capacity = 512 >= 256),
// so spinning is safe. __threadfence() = device-scope release/acquire (cross-XCD).
__device__ __forceinline__ void gridbar(int* ctr, int target) {
    __threadfence();
    __syncthreads();
    if (threadIdx.x == 0) {
        atomicAdd(ctr, 1);
        while (__hip_atomic_load(ctr, __ATOMIC_RELAXED, __HIP_MEMORY_SCOPE_AGENT) < target)
            __builtin_amdgcn_s_sleep(2);
    }
    __syncthreads();
    __threadfence();
}

// One 64-row x 128-col output tile of out[m][o] = sum_k A[m][k]*W[o][k].
__device__ __forceinline__ void gemm_tile(const float* __restrict__ A,
        const float* __restrict__ W, float* __restrict__ out, int tile, SMem& sm) {
    int tid = threadIdx.x;
    int tx = tid & 31;
    int ty = tid >> 5;
    int row0 = tile * 64;
    float acc[8][4] = {};
    for (int k0 = 0; k0 < 128; k0 += 32) {
        #pragma unroll
        for (int i = 0; i < 8; ++i) {
            int idx = tid + i * 256;
            int r = idx >> 5, k = idx & 31;
            int gr = row0 + r;
            sm.gemm.As[k][r] = (gr < N_NODES) ? A[gr * CH + k0 + k] : 0.0f;
        }
        #pragma unroll
        for (int i = 0; i < 16; ++i) {
            int idx = tid + i * 256;
            int o = idx >> 5, k = idx & 31;
            sm.gemm.Ws[k][o] = W[o * CH + k0 + k];
        }
        __syncthreads();
        #pragma unroll
        for (int kk = 0; kk < 32; ++kk) {
            float a[8], w[4];
            #pragma unroll
            for (int j = 0; j < 8; ++j) a[j] = sm.gemm.As[kk][ty * 8 + j];
            #pragma unroll
            for (int c = 0; c < 4; ++c) w[c] = sm.gemm.Ws[kk][tx * 4 + c];
            #pragma unroll
            for (int j = 0; j < 8; ++j)
                #pragma unroll
                for (int c = 0; c < 4; ++c)
                    acc[j][c] += a[j] * w[c];
        }
        __syncthreads();
    }
    #pragma unroll
    for (int j = 0; j < 8; ++j) {
        int gr = row0 + ty * 8 + j;
        if (gr < N_NODES) {
            float4 v = make_float4(acc[j][0], acc[j][1], acc[j][2], acc[j][3]);
            *reinterpret_cast<float4*>(&out[gr * CH + tx * 4]) = v;
        }
    }
}

// Aggregation phase: 32 lanes/node (float4 each), 8 nodes per block-iteration,
// grid-stride over nodes, edge loop unrolled x8 for MLP.
__device__ __forceinline__ void agg_phase(const float4* __restrict__ xw4,
        const int2* __restrict__ erec, const int* __restrict__ offs,
        const int* __restrict__ cnt, const float* __restrict__ dinv,
        const float4* __restrict__ bias4, float4* __restrict__ out4) {
    int l = threadIdx.x & 31;
    int g = threadIdx.x >> 5;
    for (int n = blockIdx.x * 8 + g; n < N_NODES; n += NBLK * 8) {
        float d = dinv[n];
        float dd = d * d;
        float4 self = xw4[n * 32 + l];
        float4 acc = make_float4(dd * self.x, dd * self.y, dd * self.z, dd * self.w);
        int start = offs[n];
        int num = cnt[n];
        int i = 0;
        for (; i + 8 <= num; i += 8) {
            int2 r[8];
            #pragma unroll
            for (int j = 0; j < 8; ++j) r[j] = erec[start + i + j];
            float4 f[8];
            #pragma unroll
            for (int j = 0; j < 8; ++j) f[j] = xw4[r[j].x * 32 + l];
            #pragma unroll
            for (int j = 0; j < 8; ++j) {
                float v = __int_as_float(r[j].y);
                acc.x += v * f[j].x; acc.y += v * f[j].y;
                acc.z += v * f[j].z; acc.w += v * f[j].w;
            }
        }
        for (; i < num; ++i) {
            int2 r = erec[start + i];
            float4 f = xw4[r.x * 32 + l];
            float v = __int_as_float(r.y);
            acc.x += v * f.x; acc.y += v * f.y; acc.z += v * f.z; acc.w += v * f.w;
        }
        float4 bb = bias4[l];
        acc.x = fmaxf(acc.x + bb.x, 0.0f);
        acc.y = fmaxf(acc.y + bb.y, 0.0f);
        acc.z = fmaxf(acc.z + bb.z, 0.0f);
        acc.w = fmaxf(acc.w + bb.w, 0.0f);
        out4[n * 32 + l] = acc;
    }
}

__global__ void init_ctr_kernel(int* ctr) { if (threadIdx.x == 0) *ctr = 0; }

__global__ __launch_bounds__(NTHR) void mega_kernel(
        const float* __restrict__ x, const int* __restrict__ ei,
        const float* __restrict__ ew,
        const float* __restrict__ W1, const float* __restrict__ b1,
        const float* __restrict__ W2, const float* __restrict__ b2,
        const float* __restrict__ conv_w, const float* __restrict__ conv_b,
        const float* __restrict__ fc_w, const float* __restrict__ fc_b,
        float* __restrict__ out,
        float* __restrict__ xw1, float* __restrict__ h1,
        float* __restrict__ xw2, float* __restrict__ h2,
        int2* __restrict__ erec, int* __restrict__ hist, float* __restrict__ dhist,
        int* __restrict__ tot, int* __restrict__ offs, float* __restrict__ dinv,
        int* __restrict__ csum, float* __restrict__ vbuf, float* __restrict__ c0,
        int* __restrict__ barctr) {
    __shared__ SMem sm;
    const int b = blockIdx.x, t = threadIdx.x;

    // ---- Phase A: hist (blocks 0..127)  ||  gemm1 + convfc-prep (128..255) ----
    if (b < NHB) {
        for (int i = t; i < N_NODES; i += NTHR) { sm.hist.h[i] = 0; sm.hist.hf[i] = 0.0f; }
        __syncthreads();
        int e0 = b * EPB;
        for (int i = t; i < EPB; i += NTHR) {
            int c = ei[N_EDGES + e0 + i];
            float w = ew[e0 + i];
            atomicAdd(&sm.hist.h[c], 1);       // LDS atomics
            atomicAdd(&sm.hist.hf[c], w);
        }
        __syncthreads();
        for (int i = t; i < N_NODES; i += NTHR) {
            hist[b * N_NODES + i] = sm.hist.h[i];
            dhist[b * N_NODES + i] = sm.hist.hf[i];
        }
    } else {
        int bb = b - NHB;
        gemm_tile(x, W1, xw1, bb, sm);
        if (bb + NHB < GTILES) gemm_tile(x, W1, xw1, bb + NHB, sm);
        if (b == NBLK - 1) {                   // conv1d+fc weight folding
            for (int i = t; i <= 384; i += NTHR) {
                if (i < 384) {
                    float s = 0.0f;
                    for (int o = 0; o < CH; ++o) s += fc_w[o] * conv_w[o * 384 + i];
                    vbuf[i] = s;
                } else {
                    float s = fc_b[0];
                    for (int o = 0; o < CH; ++o) s += fc_w[o] * conv_b[o];
                    *c0 = s;
                }
            }
        }
    }
    gridbar(barctr, NBLK * 1);

    // ---- Phase B: reduce hist -> tot, dinv, per-chunk sums ----
    if (b < NCHUNK) {
        int n = b * NTHR + t;
        int c = 0;
        if (n < N_NODES) {
            float d = 0.0f;
            #pragma unroll 4
            for (int bb = 0; bb < NHB; ++bb) {
                c += hist[bb * N_NODES + n];
                d += dhist[bb * N_NODES + n];
            }
            tot[n] = c;
            dinv[n] = rsqrtf(d + 1.0f);        // +1 = self-loop weight
        }
        int lane = t & 63, wave = t >> 6;
        int s = c;
        #pragma unroll
        for (int off = 32; off > 0; off >>= 1) s += __shfl_down(s, off, 64);
        if (lane == 0) sm.red[wave] = s;
        __syncthreads();
        if (t == 0) csum[b] = sm.red[0] + sm.red[1] + sm.red[2] + sm.red[3];
    }
    gridbar(barctr, NBLK * 2);

    // ---- Phase C: offs = exclusive prefix; hist columns -> start cursors ----
    if (b < NCHUNK) {
        if (t < NCHUNK) sm.scan.csum[t] = csum[t];
        __syncthreads();
        int base = 0;
        for (int i = 0; i < b; ++i) base += sm.scan.csum[i];
        int n = b * NTHR + t;
        int v = (n < N_NODES) ? tot[n] : 0;
        int lane = t & 63, wave = t >> 6;
        int s = v;
        #pragma unroll
        for (int off = 1; off < 64; off <<= 1) {
            int u = __shfl_up(s, off, 64);
            if (lane >= off) s += u;
        }
        if (lane == 63) sm.scan.wsum[wave] = s;
        __syncthreads();
        int wbase = 0;
        for (int i = 0; i < wave; ++i) wbase += sm.scan.wsum[i];
        if (n < N_NODES) {
            int run = base + wbase + s - v;
            offs[n] = run;
            for (int bb = 0; bb < NHB; ++bb) {
                int hh = hist[bb * N_NODES + n];
                hist[bb * N_NODES + n] = run;
                run += hh;
            }
        }
    }
    gridbar(barctr, NBLK * 3);

    // ---- Phase D: scatter edges into CSR {src,val} records ----
    if (b < NHB) {
        for (int i = t; i < N_NODES; i += NTHR) {
            sm.scat.cur[i] = hist[b * N_NODES + i];
            sm.scat.di[i] = dinv[i];
        }
        __syncthreads();
        int e0 = b * EPB;
        for (int i = t; i < EPB; i += NTHR) {
            int e = e0 + i;
            int r = ei[e];
            int c = ei[N_EDGES + e];
            int p = atomicAdd(&sm.scat.cur[c], 1);   // LDS atomic
            float v = sm.scat.di[r] * ew[e] * sm.scat.di[c];
            erec[p] = make_int2(r, __float_as_int(v));
        }
    }
    gridbar(barctr, NBLK * 4);

    // ---- Phase E: layer-1 aggregation ----
    agg_phase((const float4*)xw1, erec, offs, tot, dinv, (const float4*)b1, (float4*)h1);
    gridbar(barctr, NBLK * 5);

    // ---- Phase F: gemm2 ----
    if (b < GTILES) gemm_tile(h1, W2, xw2, b, sm);
    gridbar(barctr, NBLK * 6);

    // ---- Phase G: layer-2 aggregation ----
    agg_phase((const float4*)xw2, erec, offs, tot, dinv, (const float4*)b2, (float4*)h2);
    gridbar(barctr, NBLK * 7);

    // ---- Phase H: fused temporal conv + fc ----
    {
        int l = t & 31;
        int g = t >> 5;
        const float4* h4 = (const float4*)h2;
        // preload the 12 folded coefficients for this lane's channel quad
        float v00 = vbuf[(4 * l + 0) * 3 + 0], v01 = vbuf[(4 * l + 0) * 3 + 1], v02 = vbuf[(4 * l + 0) * 3 + 2];
        float v10 = vbuf[(4 * l + 1) * 3 + 0], v11 = vbuf[(4 * l + 1) * 3 + 1], v12 = vbuf[(4 * l + 1) * 3 + 2];
        float v20 = vbuf[(4 * l + 2) * 3 + 0], v21 = vbuf[(4 * l + 2) * 3 + 1], v22 = vbuf[(4 * l + 2) * 3 + 2];
        float v30 = vbuf[(4 * l + 3) * 3 + 0], v31 = vbuf[(4 * l + 3) * 3 + 1], v32 = vbuf[(4 * l + 3) * 3 + 2];
        float cc = *c0;
        for (int n = b * 8 + g; n < N_NODES; n += NBLK * 8) {
            float4 hm = h4[n * 32 + l];
            float p = hm.x * v01 + hm.y * v11 + hm.z * v21 + hm.w * v31;
            if (n > 0) {
                float4 ha = h4[(n - 1) * 32 + l];
                p += ha.x * v00 + ha.y * v10 + ha.z * v20 + ha.w * v30;
            }
            if (n < N_NODES - 1) {
                float4 hb = h4[(n + 1) * 32 + l];
                p += hb.x * v02 + hb.y * v12 + hb.z * v22 + hb.w * v32;
            }
            #pragma unroll
            for (int off = 16; off > 0; off >>= 1) p += __shfl_down(p, off, 32);
            if (l == 0) out[n] = p + cc;
        }
    }
}

// ---------------------------------------------------------------------------
extern "C" void kernel_launch(void* const* d_in, const int* in_sizes, int n_in,
                              void* d_out, int out_size, void* d_ws, size_t ws_size,
                              hipStream_t stream) {
    const float* x       = (const float*)d_in[0];
    const int*   ei      = (const int*)d_in[1];
    const float* ew      = (const float*)d_in[2];
    const float* W1      = (const float*)d_in[3];
    const float* b1      = (const float*)d_in[4];
    const float* W2      = (const float*)d_in[5];
    const float* b2      = (const float*)d_in[6];
    const float* conv_w  = (const float*)d_in[7];
    const float* conv_b  = (const float*)d_in[8];
    const float* fc_w    = (const float*)d_in[9];
    const float* fc_b    = (const float*)d_in[10];
    float* out = (float*)d_out;

    // Workspace (no aliasing — gemm1 overlaps the CSR build now). ~36 MB total.
    float* xw1   = (float*)d_ws;                    // 1,280,000 f
    float* h1    = xw1 + N_NODES * CH;              // 1,280,000 f
    float* xw2   = h1 + N_NODES * CH;               // 1,280,000 f
    float* h2    = xw2 + N_NODES * CH;              // 1,280,000 f
    int2*  erec  = (int2*)(h2 + N_NODES * CH);      // 640,000 x 8B
    int*   hist  = (int*)(erec + N_EDGES);          // NHB*10,000 i
    float* dhist = (float*)(hist + NHB * N_NODES);  // NHB*10,000 f
    int*   tot   = (int*)(dhist + NHB * N_NODES);   // 10,000 i
    int*   offs  = tot + N_NODES;                   // 10,000 i
    float* dinv  = (float*)(offs + N_NODES);        // 10,000 f
    int*   csum  = (int*)(dinv + N_NODES);          // NCHUNK i
    float* vbuf  = (float*)(csum + NCHUNK);         // 384 f
    float* c0    = vbuf + 384;                      // 1 f
    int*   barctr = (int*)(c0 + 1);                 // 1 i

    init_ctr_kernel<<<1, 64, 0, stream>>>(barctr);
    mega_kernel<<<NBLK, NTHR, 0, stream>>>(x, ei, ew, W1, b1, W2, b2,
                                           conv_w, conv_b, fc_w, fc_b, out,
                                           xw1, h1, xw2, h2, erec, hist, dhist,
                                           tot, offs, dinv, csum, vbuf, c0, barctr);
}